// Round 6
// baseline (217.859 us; speedup 1.0000x reference)
//
#include <hip/hip_runtime.h>

#define NN 50000
#define EE 800000
#define FF 64
#define HH 4
#define HF 256          // H*F
#define NEG_SLOPE 0.2f
#define LN_EPS 1e-5f
#define WPACK_N (4 * 8 * 64 * 8)   // 16384 bf16 elements (W B-frags)
#define NTILE (NN / 16)            // 3125 node tiles
#define TROW 264                   // LDS tile row stride (256 + 8 pad)

typedef __attribute__((ext_vector_type(8))) short s8v;    // 8 bf16 (4 VGPRs)
typedef __attribute__((ext_vector_type(4))) float f4v;    // 4 fp32 acc

__device__ __forceinline__ unsigned short f32_to_bf16_rne(float x) {
  unsigned int u = __float_as_uint(x);
  unsigned int r = u + 0x7FFFu + ((u >> 16) & 1u);
  return (unsigned short)(r >> 16);
}

__device__ __forceinline__ float readlane_f(float v, int l) {
  return __uint_as_float(
      (unsigned)__builtin_amdgcn_readlane((int)__float_as_uint(v), l));
}

// ---------------- Kernel P: fold weights + zero cnt ------------------------
// Algebraic restructure: rst_flat @ out_w == sum_h g_h @ W_h with
//   g_h[dst]   = sum_e alpha_h,e * h[src_e]          (gathered in k_gather)
//   W[hh*64+kk][c] = sum_ff fc_w[kk][hh*64+ff] * out_w[hh*64+ff][c]
// el/er reduce to h @ alv/arv with
//   alv[hh][kk] = sum_ff fc_w[kk][hh*64+ff] * attn_l[hh][ff]
// gat_bias folds exactly (fp32): outb2 = out_b + gat_bias_flat @ out_w.
// So feat (25.6 MB, 512 B/row gathers) is never materialized -- the edge
// gather reads bf16 h rows (128 B) instead: 4x less gather traffic.
__global__ __launch_bounds__(256) void k_prep(
    const float* __restrict__ fc_w, const float* __restrict__ out_w,
    const float* __restrict__ attn_l, const float* __restrict__ attn_r,
    const float* __restrict__ gat_bias, const float* __restrict__ out_b,
    unsigned short* __restrict__ wpack, float* __restrict__ alv,
    float* __restrict__ arv, float* __restrict__ outb2,
    int* __restrict__ cnt) {
  const int idx = blockIdx.x * 256 + threadIdx.x;   // < 65536
  if (idx < WPACK_N) {
    // same B-frag packing as before, with W[k][c] substituted for out_w
    const int j = idx & 7;
    const int l = (idx >> 3) & 63;
    const int t = (idx >> 9) & 7;
    const int ct = idx >> 12;
    const int k = 32 * t + (l >> 4) * 8 + j;        // 0..255 (= hh*64+kk)
    const int c = 16 * ct + (l & 15);               // 0..63
    const int hh = k >> 6, kk = k & 63;
    const float* fw = fc_w + kk * HF + hh * FF;
    const float* ow = out_w + (size_t)(hh * FF) * FF + c;
    float acc = 0.f;
#pragma unroll
    for (int ff = 0; ff < FF; ++ff) acc = fmaf(fw[ff], ow[(size_t)ff * FF], acc);
    wpack[idx] = f32_to_bf16_rne(acc);
  } else if (idx < WPACK_N + 512) {
    const int i = idx - WPACK_N;                    // 0..511
    const int hh = (i >> 6) & 3, kk = i & 63;
    const float* fw = fc_w + kk * HF + hh * FF;
    const float* at = (i < 256 ? attn_l : attn_r) + hh * FF;
    float acc = 0.f;
#pragma unroll
    for (int ff = 0; ff < FF; ++ff) acc = fmaf(fw[ff], at[ff], acc);
    (i < 256 ? alv : arv)[(hh << 6) | kk] = acc;
  } else if (idx < WPACK_N + 512 + FF) {
    const int c = idx - WPACK_N - 512;              // 0..63
    float acc = out_b[c];
    for (int k = 0; k < HF; ++k) acc = fmaf(gat_bias[k], out_w[(size_t)k * FF + c], acc);
    outb2[c] = acc;
  }
  if (idx < NN) cnt[idx] = 0;
}

// ---------------- Kernel E: hb = bf16(h) ; el/er = h @ alv/arv -------------
// One coalesced pass over h (replaces the whole feat GEMM, ~27us -> ~4us).
__global__ __launch_bounds__(256) void k_elr(
    const float* __restrict__ h, const float* __restrict__ alv,
    const float* __restrict__ arv, unsigned short* __restrict__ hb,
    float* __restrict__ el, float* __restrict__ er) {
  const int wave = threadIdx.x >> 6;
  const int lane = threadIdx.x & 63;
  const int n0 = blockIdx.x * 16 + wave * 4;
  float av[4], bv[4];
#pragma unroll
  for (int hh = 0; hh < 4; ++hh) {
    av[hh] = alv[(hh << 6) | lane];
    bv[hh] = arv[(hh << 6) | lane];
  }
#pragma unroll
  for (int r = 0; r < 4; ++r) {
    const int n = n0 + r;
    const float hv = h[(size_t)n * FF + lane];      // coalesced 256B
    hb[(size_t)n * FF + lane] = f32_to_bf16_rne(hv);
    float p[8];
#pragma unroll
    for (int hh = 0; hh < 4; ++hh) { p[hh] = hv * av[hh]; p[4 + hh] = hv * bv[hh]; }
#pragma unroll
    for (int off = 1; off < 64; off <<= 1) {
#pragma unroll
      for (int q = 0; q < 8; ++q) p[q] += __shfl_xor(p[q], off, 64);
    }
    if (lane == 0) {
      *(float4*)(el + (size_t)n * 4) = make_float4(p[0], p[1], p[2], p[3]);
      *(float4*)(er + (size_t)n * 4) = make_float4(p[4], p[5], p[6], p[7]);
    }
  }
}

// ---------------- padded-CSR build: ONE edge pass --------------------------
__global__ void k_scatter(const int* __restrict__ src,
                          const int* __restrict__ dst,
                          int* __restrict__ cnt, int* __restrict__ colp) {
  int e = blockIdx.x * blockDim.x + threadIdx.x;
  if (e < EE) {
    const int d = dst[e];
    const int pos = atomicAdd(&cnt[d], 1);
    if (pos < 64) colp[(d << 6) | pos] = src[e];
  }
}

// ------- Fused Kernel: h-gather + folded out-GEMM + LayerNorm --------------
// R0 structure (one 16-node tile/block, streaming grid, 8-batch readlane
// loop, wave-0 GEMM). Per edge: ONE 128B wave-read of hb[src] (vs 512B of
// feat), 4 FMA into g[4][64]. z via one butterfly + pre-normalized w
// (removes 4 VALU/edge + end divide; no LDS wtab -- that was R2's
// regression). GEMM multiplies by the folded W with gat_bias-folded bias.
__global__ __launch_bounds__(256) void k_gather_out(
    const unsigned short* __restrict__ hb, const float* __restrict__ el,
    const float* __restrict__ er, const int* __restrict__ cnt,
    const int* __restrict__ colp,
    const unsigned short* __restrict__ wpack, const float* __restrict__ outb2,
    const float* __restrict__ ln_g, const float* __restrict__ ln_b,
    float* __restrict__ out) {
  __shared__ unsigned short tile[16][TROW];  // 8.25 KB, rows padded +16B
  const int wave = threadIdx.x >> 6;
  const int lane = threadIdx.x & 63;
  const int n0 = blockIdx.x * 16;
  const unsigned short* fb = hb + lane;      // per-lane 2B slot of each row

#pragma unroll
  for (int r = 0; r < 4; ++r) {
    const int row = wave * 4 + r;
    const int n = n0 + row;
    const int m = cnt[n];                           // <= 64
    const float4 erv = *(const float4*)(er + (size_t)n * 4);
    int s = 0;
    float w0 = 0.f, w1 = 0.f, w2 = 0.f, w3 = 0.f;
    if (lane < m) {
      s = colp[(n << 6) | lane];                    // coalesced
      const float4 elv = *(const float4*)(el + (size_t)s * 4);
      float e0 = elv.x + erv.x, e1 = elv.y + erv.y;
      float e2 = elv.z + erv.z, e3 = elv.w + erv.w;
      e0 = e0 > 0.f ? e0 : NEG_SLOPE * e0;
      e1 = e1 > 0.f ? e1 : NEG_SLOPE * e1;
      e2 = e2 > 0.f ? e2 : NEG_SLOPE * e2;
      e3 = e3 > 0.f ? e3 : NEG_SLOPE * e3;
      w0 = __expf(e0); w1 = __expf(e1);
      w2 = __expf(e2); w3 = __expf(e3);
    }
    // softmax denominator once per node (lanes >= m hold w = 0)
    float z0 = w0, z1 = w1, z2 = w2, z3 = w3;
#pragma unroll
    for (int off = 1; off < 64; off <<= 1) {
      z0 += __shfl_xor(z0, off, 64);
      z1 += __shfl_xor(z1, off, 64);
      z2 += __shfl_xor(z2, off, 64);
      z3 += __shfl_xor(z3, off, 64);
    }
    w0 *= (z0 > 0.f ? 1.f / z0 : 0.f);
    w1 *= (z1 > 0.f ? 1.f / z1 : 0.f);
    w2 *= (z2 > 0.f ? 1.f / z2 : 0.f);
    w3 *= (z3 > 0.f ? 1.f / z3 : 0.f);

    float a0 = 0.f, a1 = 0.f, a2 = 0.f, a3 = 0.f;
    for (int e = 0; e < m; e += 8) {
#pragma unroll
      for (int j = 0; j < 8; ++j) {
        const int le = e + j;                       // < 64 always
        const int se = __builtin_amdgcn_readlane(s, le);
        const float xv = __uint_as_float(
            (unsigned)fb[(size_t)se * FF] << 16);   // 128B/wave, coalesced
        const float we0 = readlane_f(w0, le);
        const float we1 = readlane_f(w1, le);
        const float we2 = readlane_f(w2, le);
        const float we3 = readlane_f(w3, le);
        a0 = fmaf(we0, xv, a0);
        a1 = fmaf(we1, xv, a1);
        a2 = fmaf(we2, xv, a2);
        a3 = fmaf(we3, xv, a3);
      }
    }
    // g rows -> LDS tile, column layout hh*64+kk (matches W's k index)
    tile[row][lane]       = f32_to_bf16_rne(a0);
    tile[row][64 + lane]  = f32_to_bf16_rne(a1);
    tile[row][128 + lane] = f32_to_bf16_rne(a2);
    tile[row][192 + lane] = f32_to_bf16_rne(a3);
  }
  __syncthreads();
  if (wave != 0) return;

  // ---- folded out-GEMM for this 16-node tile (one wave; 32 MFMAs) ----
  const int cl = lane & 15;
  const int quad = lane >> 4;
  s8v a[8];
#pragma unroll
  for (int t = 0; t < 8; ++t)
    a[t] = *(const s8v*)(&tile[cl][32 * t + quad * 8]);

  f4v acc[4];
#pragma unroll
  for (int ct = 0; ct < 4; ++ct) {
    f4v z = {0.f, 0.f, 0.f, 0.f};
    acc[ct] = z;
#pragma unroll
    for (int t = 0; t < 8; ++t) {
      const s8v b = *(const s8v*)(wpack + ((ct * 8 + t) * 64 + lane) * 8);
      acc[ct] = __builtin_amdgcn_mfma_f32_16x16x32_bf16(a[t], b, acc[ct], 0, 0, 0);
    }
  }

  float x[4][4];
  float s1[4], s2[4];
#pragma unroll
  for (int r = 0; r < 4; ++r) { s1[r] = 0.f; s2[r] = 0.f; }
#pragma unroll
  for (int ct = 0; ct < 4; ++ct) {
    const float ob = outb2[16 * ct + cl];
#pragma unroll
    for (int r = 0; r < 4; ++r) {
      const float v = acc[ct][r] + ob;
      x[ct][r] = v;
      s1[r] += v;
      s2[r] += v * v;
    }
  }
#pragma unroll
  for (int r = 0; r < 4; ++r) {
#pragma unroll
    for (int off = 1; off < 16; off <<= 1) {
      s1[r] += __shfl_xor(s1[r], off, 64);
      s2[r] += __shfl_xor(s2[r], off, 64);
    }
  }
#pragma unroll
  for (int r = 0; r < 4; ++r) {
    const float mu = s1[r] * (1.f / 64.f);
    const float var = s2[r] * (1.f / 64.f) - mu * mu;
    const float inv = rsqrtf(var + LN_EPS);
    const int row = n0 + quad * 4 + r;
#pragma unroll
    for (int ct = 0; ct < 4; ++ct) {
      const int c = 16 * ct + cl;
      out[(size_t)row * FF + c] = (x[ct][r] - mu) * inv * ln_g[c] + ln_b[c];
    }
  }
}

// ---------------- launch ---------------------------------------------------
extern "C" void kernel_launch(void* const* d_in, const int* in_sizes, int n_in,
                              void* d_out, int out_size, void* d_ws,
                              size_t ws_size, hipStream_t stream) {
  const float* h_in   = (const float*)d_in[0];
  const int*   src    = (const int*)d_in[1];
  const int*   dst    = (const int*)d_in[2];
  const float* fc_w   = (const float*)d_in[3];
  const float* attn_l = (const float*)d_in[4];
  const float* attn_r = (const float*)d_in[5];
  const float* gbias  = (const float*)d_in[6];
  const float* out_w  = (const float*)d_in[7];
  const float* out_b  = (const float*)d_in[8];
  const float* ln_g   = (const float*)d_in[9];
  const float* ln_b   = (const float*)d_in[10];
  float* out = (float*)d_out;

  char* p = (char*)d_ws;
  auto alloc = [&](size_t bytes) {
    char* q = p;
    p += (bytes + 255) & ~(size_t)255;
    return q;
  };
  unsigned short* hb     = (unsigned short*)alloc((size_t)NN * FF * 2); // 6.4 MB
  unsigned short* wpack  = (unsigned short*)alloc((size_t)WPACK_N * 2);
  float* alv     = (float*)alloc(256 * 4);
  float* arv     = (float*)alloc(256 * 4);
  float* outb2   = (float*)alloc(64 * 4);
  float* el      = (float*)alloc((size_t)NN * HH * 4);
  float* er      = (float*)alloc((size_t)NN * HH * 4);
  int*   cnt     = (int*)alloc((size_t)NN * 4);
  int*   colp    = (int*)alloc((size_t)NN * 64 * 4);   // 12.8 MB padded CSR

  k_prep<<<256, 256, 0, stream>>>(fc_w, out_w, attn_l, attn_r, gbias, out_b,
                                  wpack, alv, arv, outb2, cnt);
  k_elr<<<NTILE, 256, 0, stream>>>(h_in, alv, arv, hb, el, er);
  k_scatter<<<(EE + 255) / 256, 256, 0, stream>>>(src, dst, cnt, colp);
  k_gather_out<<<NTILE, 256, 0, stream>>>(hb, el, er, cnt, colp, wpack,
                                          outb2, ln_g, ln_b, out);
}